// Round 1
// baseline (237.380 us; speedup 1.0000x reference)
//
#include <hip/hip_runtime.h>
#include <math.h>

#define NC 4096      // complex FFT length (N=8192 reals packed as 4096 complex)
#define TPB 256

__device__ __forceinline__ float2 cmul(float2 a, float2 b) {
    return make_float2(a.x * b.x - a.y * b.y, a.x * b.y + a.y * b.x);
}

__global__ __launch_bounds__(TPB) void snr_kernel(const float* __restrict__ x,
                                                  const float* __restrict__ targets,
                                                  float* __restrict__ out) {
    // 64 KiB LDS total: double buffer for Stockham FFT.
    __shared__ __align__(16) float2 A[NC];
    __shared__ __align__(16) float2 Bf[NC];
    const int tid = threadIdx.x;
    const int blk = blockIdx.x;

    // ---- Load row: 8192 floats = 2048 float4, coalesced 16B/lane ----
    const float4* row4 = (const float4*)(x + (size_t)blk * 8192);
    float4* A4 = (float4*)A;
#pragma unroll
    for (int k = 0; k < 8; ++k) A4[tid + k * TPB] = row4[tid + k * TPB];
    __syncthreads();

    // ---- Radix-4 Stockham DIF FFT, 6 stages, natural-order output ----
    // Invariant: s * n == NC. Reads always src[b + 1024*l], conflict-free.
    float2* src = A;
    float2* dst = Bf;
    int n = NC;
    int ls = 0;  // log2(s)
#pragma unroll
    for (int stage = 0; stage < 6; ++stage) {
        const float th = -6.283185307179586f / (float)n;
#pragma unroll
        for (int it = 0; it < 4; ++it) {
            const int b = tid + it * TPB;
            const int p = b >> ls;
            const int q = b - (p << ls);
            float2 a  = src[b];
            float2 bb = src[b + 1024];
            float2 c  = src[b + 2048];
            float2 d  = src[b + 3072];
            float2 apc = make_float2(a.x + c.x, a.y + c.y);
            float2 amc = make_float2(a.x - c.x, a.y - c.y);
            float2 bpd = make_float2(bb.x + d.x, bb.y + d.y);
            float2 bmd = make_float2(bb.x - d.x, bb.y - d.y);
            float ang = th * (float)p;
            float sn, cs;
            __sincosf(ang, &sn, &cs);
            float2 w1 = make_float2(cs, sn);      // exp(-2*pi*i*p/n)
            float2 w2 = cmul(w1, w1);
            float2 w3 = cmul(w2, w1);
            float2 o0 = make_float2(apc.x + bpd.x, apc.y + bpd.y);
            float2 o1 = cmul(make_float2(amc.x + bmd.y, amc.y - bmd.x), w1);  // (amc - i*bmd)*w1
            float2 o2 = cmul(make_float2(apc.x - bpd.x, apc.y - bpd.y), w2);
            float2 o3 = cmul(make_float2(amc.x - bmd.y, amc.y + bmd.x), w3);  // (amc + i*bmd)*w3
            const int s = 1 << ls;
            const int ob = q + (p << (ls + 2));
            dst[ob]         = o0;
            dst[ob + s]     = o1;
            dst[ob + 2 * s] = o2;
            dst[ob + 3 * s] = o3;
        }
        __syncthreads();
        float2* tmp = src; src = dst; dst = tmp;
        n >>= 2;
        ls += 2;
    }
    // 6 swaps (even) -> result Z is back in A, natural order.

    // ---- rfft split + power spectrum into P (aliases Bf) ----
    // X[k] = 0.5*[(Zk + conj(Zn)) - i*exp(-i*pi*k/4096)*(Zk - conj(Zn))], Zn = Z[(4096-k) mod 4096]
    float* P = (float*)Bf;  // needs 4097 floats = 16388 B < 32 KiB
    for (int k = tid; k <= NC; k += TPB) {
        float2 Zk = A[k & (NC - 1)];
        float2 Zn = A[(NC - k) & (NC - 1)];
        float sx = Zk.x + Zn.x, sy = Zk.y - Zn.y;   // Zk + conj(Zn)
        float dx = Zk.x - Zn.x, dy = Zk.y + Zn.y;   // Zk - conj(Zn)
        float ang = -3.14159265358979323846f * (float)k * (1.0f / 4096.0f);
        float sn, cs;
        __sincosf(ang, &sn, &cs);                    // w = (cs, sn) = exp(-i*pi*k/4096)
        float tx = dx * cs - dy * sn;
        float ty = dx * sn + dy * cs;                // t = w * d
        float Xr = 0.5f * (sx + ty);                 // -i*t = (t.y, -t.x)
        float Xi = 0.5f * (sy - tx);
        P[k] = (Xr * Xr + Xi * Xi) * (1.0f / 8192.0f);
    }
    __syncthreads();

    // ---- Noise-band sum: bins [273, 1706] ----
    float part = 0.0f;
    for (int i = 273 + tid; i < 1707; i += TPB) part += P[i];
#pragma unroll
    for (int off = 32; off > 0; off >>= 1) part += __shfl_down(part, off);
    float* red = (float*)A;  // A is free now
    const int lane = tid & 63, wid = tid >> 6;
    if (lane == 0) red[wid] = part;
    __syncthreads();

    if (tid == 0) {
        float band = red[0] + red[1] + red[2] + red[3];
        float t = targets[blk];
        const float df = 0.00244140625f;  // 10/4096, exact in fp32; f[i]=i*df exact
        int c0 = (int)(t * 409.6f) - 2;
        if (c0 < 0) c0 = 0;
        int r = c0;
        float best = fabsf(df * (float)c0 - t);
        for (int i = c0 + 1; i <= c0 + 4 && i <= 4096; ++i) {
            float dd = fabsf(df * (float)i - t);
            if (dd < best) { best = dd; r = i; }  // strict <: first-min wins, matches argmin
        }
        // signal: u = 1 at r and 2r, 0.5 at r+-1
        float S = P[r] + P[2 * r] + 0.5f * (P[r - 1] + P[r + 1]);
        // noise: band weight (1-u), with 2r-1, 2r, 2r+1 and r zeroed when inside band
        float noise = band;
        if (r <= 1706) noise -= P[r];
        if (r - 1 >= 273) noise -= 0.5f * P[r - 1];           // r-1 <= 1706 always
        if (r + 1 <= 1706) noise -= 0.5f * P[r + 1];
        if (2 * r - 1 <= 1706) noise -= P[2 * r - 1];
        if (2 * r     <= 1706) noise -= P[2 * r];
        if (2 * r + 1 <= 1706) noise -= P[2 * r + 1];
        float loss = -10.0f * log10f(S / (noise + 1.0f));
        atomicAdd(out, loss * (1.0f / 4096.0f));
    }
}

extern "C" void kernel_launch(void* const* d_in, const int* in_sizes, int n_in,
                              void* d_out, int out_size, void* d_ws, size_t ws_size,
                              hipStream_t stream) {
    const float* x = (const float*)d_in[0];    // outputs: (4096, 8192) fp32
    const float* tg = (const float*)d_in[1];   // targets: (4096, 1) fp32
    float* out = (float*)d_out;                // scalar fp32
    hipMemsetAsync(out, 0, sizeof(float), stream);
    snr_kernel<<<4096, TPB, 0, stream>>>(x, tg, out);
}

// Round 2
// 214.355 us; speedup vs baseline: 1.1074x; 1.1074x over previous
//
#include <hip/hip_runtime.h>
#include <math.h>

#define TPB 256
#define NCX 4096   // complex FFT length (8192 reals packed even/odd)

__device__ __forceinline__ float2 cmul(float2 a, float2 b) {
    return make_float2(a.x * b.x - a.y * b.y, a.x * b.y + a.y * b.x);
}

// XOR swizzle: all our LDS access patterns land at <=2-way bank aliasing (free).
__device__ __forceinline__ int sw(int i) { return i ^ ((i >> 5) & 31); }

__device__ __forceinline__ void dft4(float2& a, float2& b, float2& c, float2& d) {
    float2 t0 = make_float2(a.x + c.x, a.y + c.y);
    float2 t1 = make_float2(a.x - c.x, a.y - c.y);
    float2 t2 = make_float2(b.x + d.x, b.y + d.y);
    float2 t3 = make_float2(b.x - d.x, b.y - d.y);
    a = make_float2(t0.x + t2.x, t0.y + t2.y);
    b = make_float2(t1.x + t3.y, t1.y - t3.x);   // t1 - i*t3
    c = make_float2(t0.x - t2.x, t0.y - t2.y);
    d = make_float2(t1.x - t3.y, t1.y + t3.x);   // t1 + i*t3
}

// In-register 16-point DFT. Input v[l]; output y[m] lands at v[4*(m&3) + (m>>2)].
__device__ __forceinline__ void dft16(float2 v[16]) {
#pragma unroll
    for (int j = 0; j < 4; ++j) dft4(v[j], v[4 + j], v[8 + j], v[12 + j]);
    const float C1 = 0.9238795325112867f, S1 = 0.3826834323650898f;
    const float R2 = 0.7071067811865476f;
    // v[4b+j] *= w16^{j*b},  w16 = exp(-2*pi*i/16)
    v[5]  = cmul(v[5],  make_float2( C1, -S1));   // w^1
    v[9]  = cmul(v[9],  make_float2( R2, -R2));   // w^2
    v[13] = cmul(v[13], make_float2( S1, -C1));   // w^3
    v[6]  = cmul(v[6],  make_float2( R2, -R2));   // w^2
    v[10] = cmul(v[10], make_float2(0.f, -1.f));  // w^4
    v[14] = cmul(v[14], make_float2(-R2, -R2));   // w^6
    v[7]  = cmul(v[7],  make_float2( S1, -C1));   // w^3
    v[11] = cmul(v[11], make_float2(-R2, -R2));   // w^6
    v[15] = cmul(v[15], make_float2(-C1,  S1));   // w^9
#pragma unroll
    for (int b = 0; b < 4; ++b) dft4(v[4 * b], v[4 * b + 1], v[4 * b + 2], v[4 * b + 3]);
}

__global__ __launch_bounds__(TPB, 4) void snr_kernel(const float* __restrict__ x,
                                                     const float* __restrict__ targets,
                                                     float* __restrict__ out) {
    __shared__ float re[NCX];      // 16 KiB
    __shared__ float im[NCX];      // 16 KiB  -> 4 blocks/CU
    __shared__ float spec[6];
    __shared__ float red[4];
    __shared__ int r_sh;

    const int t = threadIdx.x;
    const int blk = blockIdx.x;

    if (t == 0) {
        float tg = targets[blk];
        const float df = 0.00244140625f;  // 10/4096, exact; f[i] = i*df exact in fp32
        int c0 = (int)(tg * 409.6f) - 2;
        if (c0 < 0) c0 = 0;
        int r = c0;
        float best = fabsf(df * (float)c0 - tg);
        for (int i = c0 + 1; i <= c0 + 4 && i <= 4096; ++i) {
            float dd = fabsf(df * (float)i - tg);
            if (dd < best) { best = dd; r = i; }  // strict <: first-min wins == argmin
        }
        r_sh = r;
    }

    // ---- Load: thread t owns c[t + 256*l]; 512B contiguous per wave per l ----
    float2 v[16];
    const float2* row = (const float2*)(x + (size_t)blk * 8192);
#pragma unroll
    for (int l = 0; l < 16; ++l) v[l] = row[t + 256 * l];

    // ======== stage 0: s=1, n=4096, p=t, writes idx=16t+m ========
    dft16(v);
    {
        float ang = -1.5339807878856412e-3f * (float)t;  // -2pi/4096 * t
        float sn, cs; __sincosf(ang, &sn, &cs);
        float2 w1 = make_float2(cs, sn);
        float2 w2 = cmul(w1, w1), w3 = cmul(w2, w1);
        float2 w4 = cmul(w2, w2), w8 = cmul(w4, w4), w12 = cmul(w8, w4);
        float2 wa[4] = {make_float2(1.f, 0.f), w1, w2, w3};
        float2 wb[4] = {make_float2(1.f, 0.f), w4, w8, w12};
#pragma unroll
        for (int m = 0; m < 16; ++m) {
            float2 y = cmul(v[4 * (m & 3) + (m >> 2)], cmul(wb[m >> 2], wa[m & 3]));
            int idx = sw(16 * t + m);
            re[idx] = y.x; im[idx] = y.y;
        }
    }
    __syncthreads();

    // ======== stage 1: s=16, n=256, p=t>>4, q=t&15 ========
#pragma unroll
    for (int l = 0; l < 16; ++l) { int idx = sw(t + 256 * l); v[l] = make_float2(re[idx], im[idx]); }
    __syncthreads();   // in-place exchange: all reads done before any writes
    dft16(v);
    {
        const int p = t >> 4, q = t & 15;
        float ang = -0.02454369260617026f * (float)p;  // -2pi/256 * p
        float sn, cs; __sincosf(ang, &sn, &cs);
        float2 w1 = make_float2(cs, sn);
        float2 w2 = cmul(w1, w1), w3 = cmul(w2, w1);
        float2 w4 = cmul(w2, w2), w8 = cmul(w4, w4), w12 = cmul(w8, w4);
        float2 wa[4] = {make_float2(1.f, 0.f), w1, w2, w3};
        float2 wb[4] = {make_float2(1.f, 0.f), w4, w8, w12};
#pragma unroll
        for (int m = 0; m < 16; ++m) {
            float2 y = cmul(v[4 * (m & 3) + (m >> 2)], cmul(wb[m >> 2], wa[m & 3]));
            int idx = sw(q + 256 * p + 16 * m);
            re[idx] = y.x; im[idx] = y.y;
        }
    }
    __syncthreads();

    // ======== stage 2: s=256, p=0 (twiddle=1), output Z[t+256m] ========
#pragma unroll
    for (int l = 0; l < 16; ++l) { int idx = sw(t + 256 * l); v[l] = make_float2(re[idx], im[idx]); }
    __syncthreads();
    dft16(v);
#pragma unroll
    for (int m = 0; m < 16; ++m) {
        float2 y = v[4 * (m & 3) + (m >> 2)];
        int idx = sw(t + 256 * m);
        re[idx] = y.x; im[idx] = y.y;
    }
    __syncthreads();

    // ======== rfft split + on-the-fly band sum & special-bin capture ========
    const int r = r_sh;
    const int r2 = 2 * r;
    float band = 0.f;
    {
        float ang = -7.669903939428206e-4f * (float)t;  // -pi/4096 * t
        float sn, cs; __sincosf(ang, &sn, &cs);
        float2 wk = make_float2(cs, sn);
        const float2 wstep = make_float2(0.9807852804032304f, -0.19509032201612825f);  // e^{-i pi/16}
#pragma unroll
        for (int m = 0; m < 16; ++m) {
            int k = t + 256 * m;
            int i1 = sw(k);
            int i2 = sw((4096 - k) & 4095);
            float2 Zk = make_float2(re[i1], im[i1]);
            float2 Zn = make_float2(re[i2], im[i2]);
            float sx = Zk.x + Zn.x, sy = Zk.y - Zn.y;  // Zk + conj(Zn)
            float dx = Zk.x - Zn.x, dy = Zk.y + Zn.y;  // Zk - conj(Zn)
            float tx = dx * wk.x - dy * wk.y;
            float ty = dx * wk.y + dy * wk.x;          // t = wk * d
            float Xr = 0.5f * (sx + ty);
            float Xi = 0.5f * (sy - tx);
            float P = (Xr * Xr + Xi * Xi) * (1.0f / 8192.0f);
            if ((unsigned)(k - 273) <= 1433u) band += P;          // k in [273,1706]
            int d1 = k - (r - 1);
            if ((unsigned)d1 < 3u) spec[d1] = P;                  // r-1, r, r+1
            int d2 = k - (r2 - 1);
            if ((unsigned)d2 < 3u) spec[3 + d2] = P;              // 2r-1, 2r, 2r+1
            wk = cmul(wk, wstep);
        }
    }

    // ======== reduce band over block ========
#pragma unroll
    for (int off = 32; off > 0; off >>= 1) band += __shfl_down(band, off);
    if ((t & 63) == 0) red[t >> 6] = band;
    __syncthreads();

    if (t == 0) {
        float bb = red[0] + red[1] + red[2] + red[3];
        float S = spec[1] + spec[4] + 0.5f * (spec[0] + spec[2]);
        float noise = bb;
        if (r <= 1706)      noise -= spec[1];
        if (r - 1 >= 273)   noise -= 0.5f * spec[0];
        if (r + 1 <= 1706)  noise -= 0.5f * spec[2];
        if (r2 - 1 <= 1706) noise -= spec[3];
        if (r2 <= 1706)     noise -= spec[4];
        if (r2 + 1 <= 1706) noise -= spec[5];
        float loss = -10.0f * log10f(S / (noise + 1.0f));
        atomicAdd(out, loss * (1.0f / 4096.0f));
    }
}

extern "C" void kernel_launch(void* const* d_in, const int* in_sizes, int n_in,
                              void* d_out, int out_size, void* d_ws, size_t ws_size,
                              hipStream_t stream) {
    const float* x = (const float*)d_in[0];    // outputs: (4096, 8192) fp32
    const float* tg = (const float*)d_in[1];   // targets: (4096, 1) fp32
    float* out = (float*)d_out;                // scalar fp32
    hipMemsetAsync(out, 0, sizeof(float), stream);
    snr_kernel<<<4096, TPB, 0, stream>>>(x, tg, out);
}